// Round 10
// baseline (80.705 us; speedup 1.0000x reference)
//
#include <hip/hip_runtime.h>
#include <hip/hip_fp16.h>
#include <math.h>

// GeometricEmbedding: B=4, N=M=3000, d_model=2, sigma_d=1.0
// out[0..12000)  float2 = p0[i] * (sum_m sin d, sum_m cos d)
// out[12000..24000)     = p1[i] * (sum_n sin d, sum_n cos d)
// d = sqrt(max(2 - 2*<p0,p1>, 0))
//
// R16: R15 (b64 table, 4 rows) measured 37.4us kernel == R0's pure-trans
// version. Budget solve: 4 random ds_read_b64/step = 128 bank-accesses
// -> ~20cyc each; 23.4 waves/CU x 46 x 4 x 20 = 36us -> LDS-UNIT-bound
// (per-CU resource, shared by 4 SIMDs), exactly replacing the trans time
// it removed. Fix: (a) pack (sin,cos) as 2xfp16 in ONE u32 -> ds_read_b32
// random gather ~9cyc (half the bank span); (b) rebalance pipes: row 3
// uses HW sin/cos (per-SIMD trans pipe, underused at 4 sqrt/step) with
// rev-scale constants (R0 math, zero extra ops). Per step: 3 gathers
// (LDS ~12us/CU) + 6 trans (~11us/SIMD) + ~42 VALU (~9.5us) - balanced.
// Predict kernel ~15-21us, dur ~57-63.

#define GB 4
#define GN 3000
#define TSIZE 2048
// Table path (rows 0-2): range [0, 6.4) rad, S = TSIZE/6.4 = 320 /rad.
// KS = S^2 = 102400; t = KS*(2-2<p,q>) so sqrt(t) = d*S = table index.
#define CKS  204800.0f              // 2*KS
#define MKS -204800.0f              // -2*KS (folded into ax,ay)
#define REVSTEP 4.9735919e-4f       // (6.4/TSIZE)/(2*pi): center step in revs
// Trans path (row 3): R0 math. t = (2-2dot)/(2pi)^2 so sqrt(t) = d in revs.
#define C2R  0.050660592f           // 2*(1/2pi)^2
#define M2R -0.050660592f

__device__ __forceinline__ float sreg(float x) {   // pin wave-uniform to SGPR
    return __int_as_float(__builtin_amdgcn_readfirstlane(__float_as_int(x)));
}

__global__ __launch_bounds__(256, 6) void geo_emb_kernel(
    const float* __restrict__ p0,
    const float* __restrict__ p1,
    float* __restrict__ out)
{
    __shared__ unsigned tab[TSIZE];             // 8 KB: fp16 sin | fp16 cos<<16

    // build table: entry i covers d in [i,i+1)/S, stores f((i+0.5)/S)
    for (int i = threadIdx.x; i < TSIZE; i += 256) {
        float rev = (i + 0.5f) * REVSTEP;       // radians/(2pi) for HW trans
        float sn = __builtin_amdgcn_sinf(rev);
        float cs = __builtin_amdgcn_cosf(rev);
        unsigned us = (unsigned)__half_as_ushort(__float2half(sn));
        unsigned uc = (unsigned)__half_as_ushort(__float2half(cs));
        tab[i] = us | (uc << 16);
    }
    __syncthreads();                            // only barrier in the kernel

    const int lane = threadIdx.x & 63;
    const int wid  = (blockIdx.x << 2) | (threadIdx.x >> 6);  // 0..5999 quads

    const bool side0 = (wid < 3000);
    const int quad = side0 ? wid : wid - 3000;
    const int i2   = quad << 2;                 // first row (0..11996), 4 | GN
    const int b    = i2 / GN;                   // magic-mul

    const float2* __restrict__ ownp = (const float2*)(side0 ? p0 : p1);
    const float2* __restrict__ othp = (const float2*)(side0 ? p1 : p0);

    const float2 pr0 = ownp[i2 + 0];
    const float2 pr1 = ownp[i2 + 1];
    const float2 pr2 = ownp[i2 + 2];
    const float2 pr3 = ownp[i2 + 3];

    const float ax0 = sreg(MKS * pr0.x), ay0 = sreg(MKS * pr0.y);
    const float ax1 = sreg(MKS * pr1.x), ay1 = sreg(MKS * pr1.y);
    const float ax2 = sreg(MKS * pr2.x), ay2 = sreg(MKS * pr2.y);
    const float ax3 = sreg(M2R * pr3.x), ay3 = sreg(M2R * pr3.y);
    const float ckv = CKS;
    const float c2r = C2R;

    float s0 = 0.f, c0 = 0.f, s1 = 0.f, c1 = 0.f;
    float s2 = 0.f, c2 = 0.f, s3 = 0.f, c3 = 0.f;

#define STEP(q) do {                                                     \
    float t0 = fmaf(ax0, (q).x, fmaf(ay0, (q).y, ckv));                  \
    float t1 = fmaf(ax1, (q).x, fmaf(ay1, (q).y, ckv));                  \
    float t2 = fmaf(ax2, (q).x, fmaf(ay2, (q).y, ckv));                  \
    float t3 = fmaf(ax3, (q).x, fmaf(ay3, (q).y, c2r));                  \
    t0 = fmaxf(t0, 0.f); t1 = fmaxf(t1, 0.f);                            \
    t2 = fmaxf(t2, 0.f); t3 = fmaxf(t3, 0.f);                            \
    float r0 = __builtin_amdgcn_sqrtf(t0);                               \
    float r1 = __builtin_amdgcn_sqrtf(t1);                               \
    float r2 = __builtin_amdgcn_sqrtf(t2);                               \
    float r3 = __builtin_amdgcn_sqrtf(t3);                               \
    unsigned j0 = (unsigned)r0; j0 = j0 < TSIZE ? j0 : TSIZE - 1;        \
    unsigned j1 = (unsigned)r1; j1 = j1 < TSIZE ? j1 : TSIZE - 1;        \
    unsigned j2 = (unsigned)r2; j2 = j2 < TSIZE ? j2 : TSIZE - 1;        \
    unsigned v0 = tab[j0];                                               \
    unsigned v1 = tab[j1];                                               \
    unsigned v2 = tab[j2];                                               \
    float sn3 = __builtin_amdgcn_sinf(r3);                               \
    float cs3 = __builtin_amdgcn_cosf(r3);                               \
    s0 += __half2float(__ushort_as_half((unsigned short)(v0)));          \
    c0 += __half2float(__ushort_as_half((unsigned short)(v0 >> 16)));    \
    s1 += __half2float(__ushort_as_half((unsigned short)(v1)));          \
    c1 += __half2float(__ushort_as_half((unsigned short)(v1 >> 16)));    \
    s2 += __half2float(__ushort_as_half((unsigned short)(v2)));          \
    c2 += __half2float(__ushort_as_half((unsigned short)(v2 >> 16)));    \
    s3 += sn3; c3 += cs3;                                                \
} while (0)

    const float2* __restrict__ qp = othp + b * GN + lane;
    float2 qA = qp[0];
    #pragma unroll 1
    for (int j = 0; j < 45; ++j) {        // compute cols lane + {0..44}*64
        float2 qB = qp[64];
        qp += 64;
        STEP(qA);
        qA = qB;
    }
    STEP(qA);                             // col lane + 45*64   (2944 total)
    if (lane < 56) {                      // cols 2944..2999
        float2 qT = qp[64];
        STEP(qT);
    }
#undef STEP

    #pragma unroll
    for (int off = 32; off >= 1; off >>= 1) {
        s0 += __shfl_down(s0, off, 64);  c0 += __shfl_down(c0, off, 64);
        s1 += __shfl_down(s1, off, 64);  c1 += __shfl_down(c1, off, 64);
        s2 += __shfl_down(s2, off, 64);  c2 += __shfl_down(c2, off, 64);
        s3 += __shfl_down(s3, off, 64);  c3 += __shfl_down(c3, off, 64);
    }

    if (lane == 0) {
        float2* o2 = (float2*)out;
        const int ob = wid << 2;          // side1 quads land at 12000+
        o2[ob + 0] = make_float2(pr0.x * s0, pr0.y * c0);
        o2[ob + 1] = make_float2(pr1.x * s1, pr1.y * c1);
        o2[ob + 2] = make_float2(pr2.x * s2, pr2.y * c2);
        o2[ob + 3] = make_float2(pr3.x * s3, pr3.y * c3);
    }
}

extern "C" void kernel_launch(void* const* d_in, const int* in_sizes, int n_in,
                              void* d_out, int out_size, void* d_ws, size_t ws_size,
                              hipStream_t stream) {
    const float* points0 = (const float*)d_in[0];
    const float* points1 = (const float*)d_in[1];
    float* out = (float*)d_out;

    dim3 grid(1500);    // 6000 waves x 4 rows = 24000 output rows
    dim3 block(256);
    geo_emb_kernel<<<grid, block, 0, stream>>>(points0, points1, out);
}

// Round 11
// 79.567 us; speedup vs baseline: 1.0143x; 1.0143x over previous
//
#include <hip/hip_runtime.h>
#include <math.h>

// GeometricEmbedding: B=4, N=M=3000, d_model=2, sigma_d=1.0
// out[0..12000)  float2 = p0[i] * (sum_m sin d, sum_m cos d)
// out[12000..24000)     = p1[i] * (sum_n sin d, sum_n cos d)
// d = sqrt(max(2 - 2*<p0,p1>, 0)); sin/cos via HW trans in revolutions
// ((1/2pi)^2 folded into the fma constants so sqrt(t) = d/2pi directly).
//
// R17: calibrated per-step model across R0/R15/R16 solves to trans ~24cyc
// EFFECTIVE and random LDS gather ~40-50cyc (width-independent) -> tables
// are dead (gather == sin+cos cost). Trans ISSUE is <=16cyc (maybe 8 on
// SIMD-32 quarter-rate), so R0 runs at 47-72% port utilization: the gap
// is latency hiding, not arithmetic. Single-eval line (R7-R12) abandoned:
// machinery reliably eats the halved-eval win. This round: R0's exact
// STEP, but columns split 2-way -> 12000 waves (3000 blocks, lb(256,8) ->
// 8 blocks/CU resident vs 5.86) for 2x latency hiding. Partials to ws;
// tiny 94-block combine kernel (proven R10 pattern) sums halves * p.
// Predict kernel 37.4 -> 23-29us + 2us combine; dur ~65-72.

#define GN 3000
#define K2 0.025330295910584444f    // (1/2pi)^2
#define C2 0.050660591821168888f    // 2*(1/2pi)^2

__device__ __forceinline__ float sreg(float x) {   // pin wave-uniform to SGPR
    return __int_as_float(__builtin_amdgcn_readfirstlane(__float_as_int(x)));
}

// 3000 blocks x 4 waves = 12000 waves; wave = (side, quad of 4 rows, col-half)
// ws[wid*4 + r] = (sum sin, sum cos) over this wave's 1500 cols for row r.
__global__ __launch_bounds__(256, 8) void geo_pair_kernel(
    const float* __restrict__ p0,
    const float* __restrict__ p1,
    float2* __restrict__ ws)
{
    const int lane = threadIdx.x & 63;
    const int wid  = (blockIdx.x << 2) | (threadIdx.x >> 6);  // 0..11999

    const bool side0 = (wid < 6000);
    const int w    = side0 ? wid : wid - 6000;  // 0..5999
    const int quad = w >> 1;                    // 0..2999 (4 output rows)
    const int h    = w & 1;                     // column half
    const int i2   = quad << 2;                 // first row (0..11996), 4 | GN
    const int b    = i2 / GN;                   // magic-mul

    const float2* __restrict__ ownp = (const float2*)(side0 ? p0 : p1);
    const float2* __restrict__ othp = (const float2*)(side0 ? p1 : p0);

    const float2 pr0 = ownp[i2 + 0];
    const float2 pr1 = ownp[i2 + 1];
    const float2 pr2 = ownp[i2 + 2];
    const float2 pr3 = ownp[i2 + 3];

    const float mm = -2.0f * K2;
    const float ax0 = sreg(mm * pr0.x), ay0 = sreg(mm * pr0.y);
    const float ax1 = sreg(mm * pr1.x), ay1 = sreg(mm * pr1.y);
    const float ax2 = sreg(mm * pr2.x), ay2 = sreg(mm * pr2.y);
    const float ax3 = sreg(mm * pr3.x), ay3 = sreg(mm * pr3.y);
    const float c2v = C2;

    float s0 = 0.f, c0 = 0.f, s1 = 0.f, c1 = 0.f;
    float s2 = 0.f, c2 = 0.f, s3 = 0.f, c3 = 0.f;

#define STEP(q) do {                                                     \
    float t0 = fmaf(ax0, (q).x, fmaf(ay0, (q).y, c2v));                  \
    float t1 = fmaf(ax1, (q).x, fmaf(ay1, (q).y, c2v));                  \
    float t2 = fmaf(ax2, (q).x, fmaf(ay2, (q).y, c2v));                  \
    float t3 = fmaf(ax3, (q).x, fmaf(ay3, (q).y, c2v));                  \
    t0 = fmaxf(t0, 0.f); t1 = fmaxf(t1, 0.f);                            \
    t2 = fmaxf(t2, 0.f); t3 = fmaxf(t3, 0.f);                            \
    float r0 = __builtin_amdgcn_sqrtf(t0);                               \
    float r1 = __builtin_amdgcn_sqrtf(t1);                               \
    float r2 = __builtin_amdgcn_sqrtf(t2);                               \
    float r3 = __builtin_amdgcn_sqrtf(t3);                               \
    s0 += __builtin_amdgcn_sinf(r0); c0 += __builtin_amdgcn_cosf(r0);    \
    s1 += __builtin_amdgcn_sinf(r1); c1 += __builtin_amdgcn_cosf(r1);    \
    s2 += __builtin_amdgcn_sinf(r2); c2 += __builtin_amdgcn_cosf(r2);    \
    s3 += __builtin_amdgcn_sinf(r3); c3 += __builtin_amdgcn_cosf(r3);    \
} while (0)

    // 1500 cols = 23 full steps (0..1471) + masked tail (1472..1499)
    const float2* __restrict__ qp = othp + b * GN + h * 1500 + lane;
    float2 qA = qp[0];
    #pragma unroll 1
    for (int j = 0; j < 22; ++j) {        // steps 0..21
        float2 qB = qp[64];
        qp += 64;
        STEP(qA);
        qA = qB;
    }
    STEP(qA);                             // step 22 (cols 1408+lane..)
    if (lane < 28) {                      // cols 1472..1499
        float2 qT = qp[64];
        STEP(qT);
    }
#undef STEP

    #pragma unroll
    for (int off = 32; off >= 1; off >>= 1) {
        s0 += __shfl_down(s0, off, 64);  c0 += __shfl_down(c0, off, 64);
        s1 += __shfl_down(s1, off, 64);  c1 += __shfl_down(c1, off, 64);
        s2 += __shfl_down(s2, off, 64);  c2 += __shfl_down(c2, off, 64);
        s3 += __shfl_down(s3, off, 64);  c3 += __shfl_down(c3, off, 64);
    }

    if (lane == 0) {
        float2* wp = ws + (wid << 2);
        wp[0] = make_float2(s0, c0);
        wp[1] = make_float2(s1, c1);
        wp[2] = make_float2(s2, c2);
        wp[3] = make_float2(s3, c3);
    }
}

// Combine: out row idx = own[idx] * (half0 + half1) partials. 94 blocks.
__global__ __launch_bounds__(256, 8) void geo_combine_kernel(
    const float* __restrict__ p0,
    const float* __restrict__ p1,
    const float2* __restrict__ ws,
    float2* __restrict__ out)
{
    const int idx = blockIdx.x * 256 + threadIdx.x;   // 0..24063
    if (idx >= 24000) return;
    const bool side0 = (idx < 12000);
    const int local = side0 ? idx : idx - 12000;      // row within side
    const int quad  = local >> 2;
    const int r     = local & 3;
    const int wid0  = (side0 ? 0 : 6000) + (quad << 1);
    const float2 a  = ws[(wid0 << 2) + r];            // half 0
    const float2 d  = ws[((wid0 + 1) << 2) + r];      // half 1
    const float2 p  = ((const float2*)(side0 ? p0 : p1))[local];
    out[idx] = make_float2(p.x * (a.x + d.x), p.y * (a.y + d.y));
}

extern "C" void kernel_launch(void* const* d_in, const int* in_sizes, int n_in,
                              void* d_out, int out_size, void* d_ws, size_t ws_size,
                              hipStream_t stream) {
    const float* points0 = (const float*)d_in[0];
    const float* points1 = (const float*)d_in[1];

    // ws usage: 12000 * 4 float2 = 384 KB
    geo_pair_kernel<<<dim3(3000), dim3(256), 0, stream>>>(
        points0, points1, (float2*)d_ws);
    geo_combine_kernel<<<dim3(94), dim3(256), 0, stream>>>(
        points0, points1, (const float2*)d_ws, (float2*)d_out);
}